// Round 1
// baseline (355.602 us; speedup 1.0000x reference)
//
#include <hip/hip_runtime.h>
#include <hip/hip_bf16.h>

// Shapes (fixed): B=8, Cin=512, N=2048, Ck=256, Co=512.
// Strategy: hi/lo bf16 split (3-MFMA fp32 emulation) for projections + QK^T;
// plain bf16 for P*V. 5 kernels: transpose/convert, W convert, 2 GEMMs, flash.

typedef __bf16 bf16;
typedef __bf16 bf16x8 __attribute__((ext_vector_type(8)));
typedef __bf16 bf16x4 __attribute__((ext_vector_type(4)));
typedef float  f32x4  __attribute__((ext_vector_type(4)));

#define B_   8
#define N_   2048
#define CIN_ 512
#define CO_  512

__device__ __forceinline__ f32x4 mfma16(bf16x8 a, bf16x8 b, f32x4 c) {
  return __builtin_amdgcn_mfma_f32_16x16x32_bf16(a, b, c, 0, 0, 0);
}

__device__ __forceinline__ void gld_lds16(const bf16* g, bf16* l) {
  __builtin_amdgcn_global_load_lds(
      (const __attribute__((address_space(1))) void*)g,
      (__attribute__((address_space(3))) void*)l,
      16, 0, 0);
}

// ---------------- kernel 1: x (B,Cin,N) f32 -> xt (B,N,Cin) hi/lo bf16 ------
__global__ __launch_bounds__(256) void xt_kernel(const float* __restrict__ x,
                                                 bf16* __restrict__ xt_h,
                                                 bf16* __restrict__ xt_l) {
  __shared__ float tile[32][33];
  const int b = blockIdx.z;
  const int n0 = blockIdx.x * 32, c0 = blockIdx.y * 32;
  const int tx = threadIdx.x, ty = threadIdx.y;  // (32, 8)
  const float* xp = x + (size_t)b * CIN_ * N_;
#pragma unroll
  for (int j = 0; j < 4; j++)
    tile[ty + 8 * j][tx] = xp[(size_t)(c0 + ty + 8 * j) * N_ + n0 + tx];
  __syncthreads();
#pragma unroll
  for (int j = 0; j < 4; j++) {
    const int nl = ty + 8 * j, cl = tx;
    const float v = tile[cl][nl];
    const bf16 h = (bf16)v;
    const size_t o = (size_t)b * N_ * CIN_ + (size_t)(n0 + nl) * CIN_ + c0 + cl;
    xt_h[o] = h;
    xt_l[o] = (bf16)(v - (float)h);
  }
}

// ---------------- kernel 2: W rows [Wq(256); Wk(256); Wv(512)] -> hi/lo -----
__global__ __launch_bounds__(256) void w_kernel(const float* __restrict__ Wq,
                                                const float* __restrict__ Wk,
                                                const float* __restrict__ Wv,
                                                bf16* __restrict__ w_h,
                                                bf16* __restrict__ w_l) {
  const int idx = blockIdx.x * 256 + threadIdx.x;  // < 1024*512
  const int row = idx >> 9;
  float v;
  if (row < 256)       v = Wq[idx];
  else if (row < 512)  v = Wk[idx - 256 * 512];
  else                 v = Wv[idx - 512 * 512];
  const bf16 h = (bf16)v;
  w_h[idx] = h;
  w_l[idx] = (bf16)(v - (float)h);
}

// ---------------- kernel 3/4: hi/lo GEMM, D[row,col] = sum_k A[row,k]B[col,k]
// 128x128 tile, BK=32, 4 waves (2x2 of 64x64), double-buffered LDS,
// global_load_lds width-16. D written as hi/lo bf16 (lo optional).
__global__ __launch_bounds__(256) void gemm_hilo(
    const bf16* __restrict__ Ah, const bf16* __restrict__ Al, size_t sA,
    const bf16* __restrict__ Bh, const bf16* __restrict__ Bl, size_t sB,
    bf16* __restrict__ Dh, bf16* __restrict__ Dl, size_t sD,
    int lda, int ldb, int ldd, int store_lo) {
  __shared__ bf16 smA[2][2][128 * 32];  // [buf][hi/lo][row][k]
  __shared__ bf16 smB[2][2][128 * 32];  // [buf][hi/lo][col][k]
  const int tid = threadIdx.x;
  const int wave = tid >> 6, lane = tid & 63;
  const int l15 = lane & 15, l4 = lane >> 4;
  const int bz = blockIdx.z;
  const int row0 = blockIdx.x * 128, col0 = blockIdx.y * 128;
  const bf16* pAh = Ah + (size_t)bz * sA + (size_t)row0 * lda;
  const bf16* pAl = Al + (size_t)bz * sA + (size_t)row0 * lda;
  const bf16* pBh = Bh + (size_t)bz * sB + (size_t)col0 * ldb;
  const bf16* pBl = Bl + (size_t)bz * sB + (size_t)col0 * ldb;

  auto stage = [&](int buf, int kt) {
    const int k0 = kt * 32;
#pragma unroll
    for (int i = 0; i < 2; i++) {
      const int sb = i * 256 + wave * 64;
      const int s = sb + lane;
      const int r = s >> 2, kseg = (s & 3) * 8;
      gld_lds16(pAh + (size_t)r * lda + k0 + kseg, &smA[buf][0][sb * 8]);
    }
#pragma unroll
    for (int i = 0; i < 2; i++) {
      const int sb = i * 256 + wave * 64;
      const int s = sb + lane;
      const int r = s >> 2, kseg = (s & 3) * 8;
      gld_lds16(pAl + (size_t)r * lda + k0 + kseg, &smA[buf][1][sb * 8]);
    }
#pragma unroll
    for (int i = 0; i < 2; i++) {
      const int sb = i * 256 + wave * 64;
      const int s = sb + lane;
      const int c = s >> 2, kseg = (s & 3) * 8;
      gld_lds16(pBh + (size_t)c * ldb + k0 + kseg, &smB[buf][0][sb * 8]);
    }
#pragma unroll
    for (int i = 0; i < 2; i++) {
      const int sb = i * 256 + wave * 64;
      const int s = sb + lane;
      const int c = s >> 2, kseg = (s & 3) * 8;
      gld_lds16(pBl + (size_t)c * ldb + k0 + kseg, &smB[buf][1][sb * 8]);
    }
  };

  f32x4 acc[4][4];
  const f32x4 zero = {0.f, 0.f, 0.f, 0.f};
#pragma unroll
  for (int i = 0; i < 4; i++)
#pragma unroll
    for (int j = 0; j < 4; j++) acc[i][j] = zero;

  const int wrow = (wave >> 1) * 64, wcol = (wave & 1) * 64;
  stage(0, 0);
  __syncthreads();
  int buf = 0;
  for (int kt = 0; kt < 16; kt++) {
    if (kt < 15) stage(buf ^ 1, kt + 1);
    bf16x8 afh[4], afl[4], bfh[4], bfl[4];
    const int kk = l4 * 8;
#pragma unroll
    for (int f = 0; f < 4; f++) {
      const int ar = wrow + f * 16 + l15;
      afh[f] = *(const bf16x8*)&smA[buf][0][ar * 32 + kk];
      afl[f] = *(const bf16x8*)&smA[buf][1][ar * 32 + kk];
      const int bc = wcol + f * 16 + l15;
      bfh[f] = *(const bf16x8*)&smB[buf][0][bc * 32 + kk];
      bfl[f] = *(const bf16x8*)&smB[buf][1][bc * 32 + kk];
    }
#pragma unroll
    for (int fi = 0; fi < 4; fi++)
#pragma unroll
      for (int fj = 0; fj < 4; fj++) {
        f32x4 c = acc[fi][fj];
        c = mfma16(afh[fi], bfh[fj], c);
        c = mfma16(afh[fi], bfl[fj], c);
        c = mfma16(afl[fi], bfh[fj], c);
        acc[fi][fj] = c;
      }
    __syncthreads();
    buf ^= 1;
  }
  bf16* pDh = Dh + (size_t)bz * sD;
  bf16* pDl = Dl + (size_t)bz * sD;
#pragma unroll
  for (int fi = 0; fi < 4; fi++)
#pragma unroll
    for (int fj = 0; fj < 4; fj++)
#pragma unroll
      for (int r = 0; r < 4; r++) {
        const int row = row0 + wrow + fi * 16 + l4 * 4 + r;
        const int col = col0 + wcol + fj * 16 + l15;
        const float v = acc[fi][fj][r];
        const bf16 h = (bf16)v;
        pDh[(size_t)row * ldd + col] = h;
        if (store_lo) pDl[(size_t)row * ldd + col] = (bf16)(v - (float)h);
      }
}

// ---------------- kernel 5: flash attention ---------------------------------
// grid (32 nblocks, 8 batch), 4 waves. Wave owns 16 n-rows, sweeps all m.
// S^T = mfma(K, Q) so lane holds column n; online softmax in-register.
// K LDS swizzle: elem ^= ((m&7)<<3) within row (breaks 512B-stride conflict).
// V LDS swizzle: byte ^= ((o&7)<<4) (perfect bank spread for [o][32m] reads).
// Both realized by pre-permuting the *global source* (gld_lds dest is linear).
__global__ __launch_bounds__(256) void flash_kernel(
    const bf16* __restrict__ qkt_h, const bf16* __restrict__ qkt_l,
    const bf16* __restrict__ vmat, float* __restrict__ out) {
  __shared__ bf16 sK[2][2][32 * 256];  // [buf][hi/lo][m][k] (swizzled)
  __shared__ bf16 sV[2][512 * 32];     // [buf][o][m] (swizzled)
  __shared__ bf16 sP[4][16 * 32];      // [wave][n][m]
  const int tid = threadIdx.x, wave = tid >> 6, lane = tid & 63;
  const int l15 = lane & 15, l4 = lane >> 4;
  const int b = blockIdx.y, nb = blockIdx.x;
  const int n0 = nb * 64 + wave * 16;
  const bf16* qh_base = qkt_h + (size_t)b * N_ * 512;
  const bf16* ql_base = qkt_l + (size_t)b * N_ * 512;
  const bf16* v_base = vmat + (size_t)b * CO_ * N_;

  // Q fragments in registers: 16 n-rows x 256 k, hi/lo
  bf16x8 qh[8], ql[8];
  {
    const int nr = n0 + l15;
#pragma unroll
    for (int ks = 0; ks < 8; ks++) {
      const size_t off = (size_t)nr * 512 + ks * 32 + l4 * 8;
      qh[ks] = *(const bf16x8*)(qh_base + off);
      ql[ks] = *(const bf16x8*)(ql_base + off);
    }
  }
  f32x4 acc[32];
  const f32x4 zero = {0.f, 0.f, 0.f, 0.f};
#pragma unroll
  for (int i = 0; i < 32; i++) acc[i] = zero;
  float run_m = -3e38f, run_l = 0.f;

  auto stage = [&](int bufi, int mt) {
    const int m0 = mt * 32;
#pragma unroll
    for (int h = 0; h < 2; h++) {
      const bf16* src = (h ? ql_base : qh_base) + 256;  // K cols 256..511
#pragma unroll
      for (int i = 0; i < 4; i++) {
        const int sb = i * 256 + wave * 64, s = sb + lane;
        const int m = s >> 5;
        const int kseg = ((s & 31) * 8) ^ ((m & 7) << 3);
        gld_lds16(src + (size_t)(m0 + m) * 512 + kseg, &sK[bufi][h][sb * 8]);
      }
    }
#pragma unroll
    for (int i = 0; i < 8; i++) {
      const int sb = i * 256 + wave * 64, s = sb + lane;
      const int Lb = s * 16;
      const int o = ((Lb >> 7) << 1) | (((Lb >> 6) ^ (Lb >> 8)) & 1);
      const int mseg = ((Lb ^ ((o & 7) << 4)) & 63) >> 1;
      gld_lds16(v_base + (size_t)o * N_ + m0 + mseg, &sV[bufi][sb * 8]);
    }
  };

  stage(0, 0);
  __syncthreads();
  int buf = 0;
  for (int mt = 0; mt < 64; mt++) {
    if (mt < 63) stage(buf ^ 1, mt + 1);
    // S^T (two 16m x 16n fragments), hi/lo 3-term
    f32x4 sfr[2];
#pragma unroll
    for (int ms = 0; ms < 2; ms++) {
      f32x4 aA = zero, aB = zero;
      const int krow = ms * 16 + l15;
      const int swz = (krow & 7) << 3;
      const bf16* kh_p = &sK[buf][0][krow * 256];
      const bf16* kl_p = &sK[buf][1][krow * 256];
#pragma unroll
      for (int ks = 0; ks < 8; ks++) {
        const int ke = (ks * 32 + l4 * 8) ^ swz;
        const bf16x8 kh = *(const bf16x8*)(kh_p + ke);
        const bf16x8 kl = *(const bf16x8*)(kl_p + ke);
        aA = mfma16(kh, qh[ks], aA);
        aB = mfma16(kh, ql[ks], aB);
        aB = mfma16(kl, qh[ks], aB);
      }
      sfr[ms] = aA + aB;
    }
    // online softmax over m (lane owns column n = n0 + l15)
    float tmax = -3e38f;
#pragma unroll
    for (int ms = 0; ms < 2; ms++)
#pragma unroll
      for (int r = 0; r < 4; r++) tmax = fmaxf(tmax, sfr[ms][r]);
    tmax = fmaxf(tmax, __shfl_xor(tmax, 16));
    tmax = fmaxf(tmax, __shfl_xor(tmax, 32));
    const float nm = fmaxf(run_m, tmax);
    const float corr = __expf(run_m - nm);
    float tsum = 0.f;
#pragma unroll
    for (int ms = 0; ms < 2; ms++) {
      bf16x4 pk;
#pragma unroll
      for (int r = 0; r < 4; r++) {
        const float p = __expf(sfr[ms][r] - nm);
        tsum += p;
        pk[r] = (bf16)p;
      }
      *(bf16x4*)&sP[wave][l15 * 32 + ms * 16 + l4 * 4] = pk;
    }
    tsum += __shfl_xor(tsum, 16);
    tsum += __shfl_xor(tsum, 32);
    run_l = run_l * corr + tsum;
    run_m = nm;
#pragma unroll
    for (int i = 0; i < 32; i++) acc[i] = acc[i] * corr;
    // PV: out[o, n] += sum_m P[n,m] V[o,m]; A=V frag, B=P^T frag
    const bf16x8 pf = *(const bf16x8*)&sP[wave][l15 * 32 + l4 * 8];
#pragma unroll
    for (int of = 0; of < 32; of++) {
      const int o = of * 16 + l15;
      const int vbyte = (o * 64 + l4 * 16) ^ ((o & 7) << 4);
      const bf16x8 vf = *(const bf16x8*)((const bf16*)sV[buf] + (vbyte >> 1));
      acc[of] = mfma16(vf, pf, acc[of]);
    }
    __syncthreads();
    buf ^= 1;
  }
  const float inv = 1.f / run_l;
  float* obase = out + (size_t)b * CO_ * N_;
#pragma unroll
  for (int of = 0; of < 32; of++)
#pragma unroll
    for (int r = 0; r < 4; r++) {
      const int o = of * 16 + l4 * 4 + r;
      obase[(size_t)o * N_ + n0 + l15] = acc[of][r] * inv;
    }
}

// ---------------- launcher ---------------------------------------------------
extern "C" void kernel_launch(void* const* d_in, const int* in_sizes, int n_in,
                              void* d_out, int out_size, void* d_ws,
                              size_t ws_size, hipStream_t stream) {
  const float* x = (const float*)d_in[0];
  const float* Wq = (const float*)d_in[1];
  const float* Wk = (const float*)d_in[2];
  const float* Wv = (const float*)d_in[3];
  float* out = (float*)d_out;
  bf16* ws = (bf16*)d_ws;

  const size_t XT = (size_t)B_ * N_ * CIN_;  // 8388608 elems
  const size_t XTB = (size_t)N_ * CIN_;      // per-batch stride 1048576
  bf16* xt_h = ws;
  bf16* xt_l = ws + XT;
  bf16* qk_h = ws + 2 * XT;
  bf16* qk_l = ws + 3 * XT;
  bf16* v_h = ws + 4 * XT;
  bf16* v_l = ws + 5 * XT;
  bf16* w_h = ws + 6 * XT;
  bf16* w_l = w_h + 1024 * 512;
  // total ws use: 6*16.78MB + 2*1.05MB = ~102.8 MB

  xt_kernel<<<dim3(64, 16, 8), dim3(32, 8, 1), 0, stream>>>(x, xt_h, xt_l);
  w_kernel<<<dim3(2048), dim3(256), 0, stream>>>(Wq, Wk, Wv, w_h, w_l);
  // QKt (B, N, 512): rows n, cols (Q|K)
  gemm_hilo<<<dim3(16, 4, 8), dim3(256), 0, stream>>>(
      xt_h, xt_l, XTB, w_h, w_l, (size_t)0, qk_h, qk_l, XTB, 512, 512, 512, 1);
  // V (B, 512, N): rows o, cols n
  gemm_hilo<<<dim3(4, 16, 8), dim3(256), 0, stream>>>(
      w_h + 512 * 512, w_l + 512 * 512, (size_t)0, xt_h, xt_l, XTB, v_h, v_l,
      (size_t)(CO_ * N_), 512, 512, 2048, 0);
  flash_kernel<<<dim3(32, 8), dim3(256), 0, stream>>>(qk_h, qk_l, v_h, out);
}